// Round 1
// baseline (311.142 us; speedup 1.0000x reference)
//
#include <hip/hip_runtime.h>
#include <stdint.h>

#define NROWS 8192
#define MCOLS 8192
#define KDIM  256

typedef __bf16 bf16x8 __attribute__((ext_vector_type(8)));
typedef float  floatx4 __attribute__((ext_vector_type(4)));

__device__ __forceinline__ unsigned short f32_to_bf16_rne(float f) {
    unsigned int u = __float_as_uint(f);
    u += 0x7FFFu + ((u >> 16) & 1u);   // round-to-nearest-even
    return (unsigned short)(u >> 16);
}
__device__ __forceinline__ float bf16_to_f32(unsigned short h) {
    return __uint_as_float(((unsigned int)h) << 16);
}

// async 16B global -> LDS (wave-uniform base + lane*16 pattern required)
__device__ __forceinline__ void async16(const void* g, void* l) {
    __builtin_amdgcn_global_load_lds(
        (const __attribute__((address_space(1))) unsigned int*)g,
        (__attribute__((address_space(3))) unsigned int*)l,
        16, 0, 0);
}

// ---------------- kernel 1: alpha = softmax(alpha_raw^2), sa = sqrt(alpha) ----
__global__ void prep_alpha(const float* __restrict__ araw, float* __restrict__ sa) {
    __shared__ float buf[256];
    int d = threadIdx.x;
    float z = araw[d];
    z = z * z;
    buf[d] = z;
    __syncthreads();
    for (int s = 128; s > 0; s >>= 1) {
        if (d < s) buf[d] = fmaxf(buf[d], buf[d + s]);
        __syncthreads();
    }
    float mx = buf[0];
    __syncthreads();
    float e = __expf(z - mx);
    buf[d] = e;
    __syncthreads();
    for (int s = 128; s > 0; s >>= 1) {
        if (d < s) buf[d] += buf[d + s];
        __syncthreads();
    }
    float sum = buf[0];
    sa[d] = sqrtf(e / sum);
}

// ---------------- kernel 2: scale rows by sa, round to bf16, norms from rounded
__global__ void prep_rows(const float* __restrict__ x, const float* __restrict__ sa,
                          unsigned short* __restrict__ mat, float* __restrict__ rnorm) {
    __shared__ float buf[256];
    int row = blockIdx.x;
    int d = threadIdx.x;
    float v = x[(size_t)row * KDIM + d] * sa[d];
    unsigned short h = f32_to_bf16_rne(v);
    mat[(size_t)row * KDIM + d] = h;
    float fv = bf16_to_f32(h);
    buf[d] = fv * fv;
    __syncthreads();
    for (int s = 128; s > 0; s >>= 1) {
        if (d < s) buf[d] += buf[d + s];
        __syncthreads();
    }
    if (d == 0) rnorm[row] = buf[0];
}

// ---------------- kernel 3: NT-GEMM + fused RBF epilogue ---------------------
// C[i,j] = sum_k A[i,k]*B[j,k];  out = var*exp(-0.5*max(ra_i - 2C + rb_j, 0))
// Tile 128x128, BK=64, 4 waves (2x2), each wave 64x64 via 4x4 of 16x16x32 MFMA.
// LDS tiles stored as 16B chunks, slot = row*8 + (kchunk ^ (row&7))  (XOR swizzle:
// keeps global_load_lds lane-consecutive AND makes ds_read_b128 conflict-free).
__global__ __launch_bounds__(256) void rbf_gemm(
    const unsigned short* __restrict__ A, const unsigned short* __restrict__ B,
    const float* __restrict__ ra, const float* __restrict__ rb,
    const float* __restrict__ vraw, float* __restrict__ out)
{
    __shared__ unsigned short As[128 * 64];
    __shared__ unsigned short Bs[128 * 64];

    const int tid  = threadIdx.x;
    const int lane = tid & 63;
    const int wave = tid >> 6;
    const int bm = blockIdx.y;   // row block (x1)
    const int bn = blockIdx.x;   // col block (x2)
    const int wm = (wave & 1) * 64;
    const int wn = (wave >> 1) * 64;
    const int quad = lane >> 4;
    const int l15  = lane & 15;

    floatx4 acc[4][4];
#pragma unroll
    for (int i = 0; i < 4; i++)
#pragma unroll
        for (int j = 0; j < 4; j++) acc[i][j] = (floatx4)0.0f;

    for (int k0 = 0; k0 < KDIM; k0 += 64) {
#pragma unroll
        for (int it = 0; it < 4; ++it) {
            int c   = it * 256 + tid;      // 16B chunk index 0..1023
            int row = c >> 3;              // tile row 0..127
            int kc  = c & 7;               // chunk-of-8-bf16 within BK=64
            int gkc = kc ^ (row & 7);      // XOR swizzle on the global side
            const unsigned short* gA = A + (size_t)(bm * 128 + row) * KDIM + k0 + gkc * 8;
            const unsigned short* gB = B + (size_t)(bn * 128 + row) * KDIM + k0 + gkc * 8;
            async16(gA, &As[c * 8]);
            async16(gB, &Bs[c * 8]);
        }
        __syncthreads();

#pragma unroll
        for (int ks = 0; ks < 2; ++ks) {
            bf16x8 af[4], bfr[4];
            int kc = ks * 4 + quad;        // k = ks*32 + quad*8 -> chunk index
#pragma unroll
            for (int t = 0; t < 4; ++t) {
                int m  = wm + t * 16 + l15;
                int sa_ = m * 8 + (kc ^ (m & 7));
                af[t]  = *(const bf16x8*)&As[sa_ * 8];
                int n  = wn + t * 16 + l15;
                int sb_ = n * 8 + (kc ^ (n & 7));
                bfr[t] = *(const bf16x8*)&Bs[sb_ * 8];
            }
#pragma unroll
            for (int ti = 0; ti < 4; ++ti)
#pragma unroll
                for (int tj = 0; tj < 4; ++tj)
                    acc[ti][tj] = __builtin_amdgcn_mfma_f32_16x16x32_bf16(
                        af[ti], bfr[tj], acc[ti][tj], 0, 0, 0);
        }
        __syncthreads();
    }

    // epilogue: C/D layout col = lane&15, row = quad*4 + reg
    float variance = vraw[0] * vraw[0];
    float rbv[4];
#pragma unroll
    for (int tj = 0; tj < 4; ++tj) rbv[tj] = rb[bn * 128 + wn + tj * 16 + l15];
#pragma unroll
    for (int ti = 0; ti < 4; ++ti) {
        int rowbase = bm * 128 + wm + ti * 16 + quad * 4;
        float rav[4];
#pragma unroll
        for (int r = 0; r < 4; ++r) rav[r] = ra[rowbase + r];
#pragma unroll
        for (int tj = 0; tj < 4; ++tj) {
            int col = bn * 128 + wn + tj * 16 + l15;
#pragma unroll
            for (int r = 0; r < 4; ++r) {
                float s = rav[r] + rbv[tj] - 2.0f * acc[ti][tj][r];
                s = fmaxf(s, 0.0f);
                out[(size_t)(rowbase + r) * MCOLS + col] = variance * __expf(-0.5f * s);
            }
        }
    }
}

extern "C" void kernel_launch(void* const* d_in, const int* in_sizes, int n_in,
                              void* d_out, int out_size, void* d_ws, size_t ws_size,
                              hipStream_t stream) {
    const float* x1   = (const float*)d_in[0];
    const float* x2   = (const float*)d_in[1];
    const float* araw = (const float*)d_in[2];
    const float* vraw = (const float*)d_in[3];
    float* out = (float*)d_out;

    char* ws = (char*)d_ws;
    float* sa = (float*)ws;                               // 256 f32   @ 0
    float* ra = (float*)(ws + 1024);                      // 8192 f32  @ 1 KiB
    float* rb = (float*)(ws + 1024 + 32768);              // 8192 f32
    unsigned short* Amat = (unsigned short*)(ws + 66560);                         // 4 MiB bf16
    unsigned short* Bmat = (unsigned short*)(ws + 66560 + (size_t)NROWS * KDIM * 2); // 4 MiB bf16

    prep_alpha<<<1, 256, 0, stream>>>(araw, sa);
    prep_rows<<<NROWS, 256, 0, stream>>>(x1, sa, Amat, ra);
    prep_rows<<<MCOLS, 256, 0, stream>>>(x2, sa, Bmat, rb);

    dim3 grid(MCOLS / 128, NROWS / 128);
    rbf_gemm<<<grid, 256, 0, stream>>>(Amat, Bmat, ra, rb, vraw, out);
}